// Round 1
// 1000.551 us; speedup vs baseline: 1.1971x; 1.1971x over previous
//
#include <hip/hip_runtime.h>

#define N_SRC0   286000
#define N_DST0   11000
#define N_E0     275000
#define N_DST1   1000
#define N_E1     10000
#define IN_FEATS 602
#define N_HIDDEN 256
#define N_CLASSES 41

#define KP 608            // IN_FEATS padded to multiple of 32 (mfma K)
#define MP 11008          // N_DST0 padded to multiple of 64 (tile M)
#define LDT 40            // LDS row length in ushorts: 32 + 8 pad -> 80B rows, 2-way bank alias (free)

typedef unsigned short u16;
typedef __attribute__((ext_vector_type(8))) short short8;
typedef __attribute__((ext_vector_type(4))) float f32x4;

__device__ inline void split_bf16(float v, u16& hi, u16& lo) {
    unsigned u = __float_as_uint(v);
    unsigned r = u + 0x7FFFu + ((u >> 16) & 1u);      // RNE to bf16
    hi = (u16)(r >> 16);
    float vhi = __uint_as_float((unsigned)hi << 16);
    float vl = v - vhi;
    unsigned u2 = __float_as_uint(vl);
    unsigned r2 = u2 + 0x7FFFu + ((u2 >> 16) & 1u);
    lo = (u16)(r2 >> 16);
}

// -------- CSR build: count, scan, fill --------

__global__ void count_kernel(const int* __restrict__ d0, int n0, int* __restrict__ c0,
                             const int* __restrict__ d1, int n1, int* __restrict__ c1) {
    int i = blockIdx.x * blockDim.x + threadIdx.x;
    if (i < n0) {
        atomicAdd(&c0[d0[i]], 1);
    } else {
        int j = i - n0;
        if (j < n1) atomicAdd(&c1[d1[j]], 1);
    }
}

__global__ void scan_kernel(const int* __restrict__ cnt0, int* __restrict__ off0, int n0_,
                            const int* __restrict__ cnt1, int* __restrict__ off1, int n1_) {
    const int* cnt; int* off; int n;
    if (blockIdx.x == 0) { cnt = cnt0; off = off0; n = n0_; }
    else                 { cnt = cnt1; off = off1; n = n1_; }
    __shared__ int sums[1024];
    int tid = threadIdx.x;
    int chunk = (n + 1023) >> 10;
    int start = tid * chunk;
    int end = min(start + chunk, n);
    int s = 0;
    for (int i = start; i < end; i++) s += cnt[i];
    sums[tid] = s;
    __syncthreads();
    for (int d = 1; d < 1024; d <<= 1) {
        int v = (tid >= d) ? sums[tid - d] : 0;
        __syncthreads();
        sums[tid] += v;
        __syncthreads();
    }
    int run = (tid > 0) ? sums[tid - 1] : 0;
    for (int i = start; i < end; i++) { off[i] = run; run += cnt[i]; }
    if (tid == 1023) off[n] = run;
}

__global__ void fill_kernel(const int* __restrict__ s0, const int* __restrict__ d0, int n0,
                            const int* __restrict__ off0, int* __restrict__ cur0, int* __restrict__ csr0,
                            const int* __restrict__ s1, const int* __restrict__ d1, int n1,
                            const int* __restrict__ off1, int* __restrict__ cur1, int* __restrict__ csr1) {
    int i = blockIdx.x * blockDim.x + threadIdx.x;
    if (i < n0) {
        int d = d0[i];
        int p = atomicAdd(&cur0[d], 1);
        csr0[off0[d] + p] = s0[i];
    } else {
        int j = i - n0;
        if (j < n1) {
            int d = d1[j];
            int p = atomicAdd(&cur1[d], 1);
            csr1[off1[d] + p] = s1[j];
        }
    }
}

// -------- split-bf16 conversion: x[:N_DST0] -> hi/lo planes [MP][KP] --------
__global__ void xconv_kernel(const float* __restrict__ x,
                             u16* __restrict__ xhi, u16* __restrict__ xlo) {
    int idx = blockIdx.x * blockDim.x + threadIdx.x;   // over N_DST0*KP
    if (idx >= N_DST0 * KP) return;
    int row = idx / KP, k = idx - row * KP;
    float v = (k < IN_FEATS) ? x[(size_t)row * IN_FEATS + k] : 0.f;
    u16 hi, lo; split_bf16(v, hi, lo);
    xhi[idx] = hi; xlo[idx] = lo;
}

// -------- weight conversion: W[k][n] fp32 -> wt[part][plane][n][KP] bf16 (n-major) --------
__global__ void wconv_kernel(const float* __restrict__ Wself, const float* __restrict__ Wneigh,
                             u16* __restrict__ wt) {
    int idx = blockIdx.x * blockDim.x + threadIdx.x;   // over 2*KP*256, n fastest (coalesced read)
    if (idx >= 2 * KP * 256) return;
    int part = idx / (KP * 256);
    int rem  = idx - part * (KP * 256);
    int k = rem / 256;
    int n = rem - k * 256;
    float v = (k < IN_FEATS) ? (part ? Wneigh[(size_t)k * 256 + n] : Wself[(size_t)k * 256 + n]) : 0.f;
    u16 hi, lo; split_bf16(v, hi, lo);
    u16* base = wt + (size_t)part * 2 * 256 * KP;
    base[(size_t)n * KP + k] = hi;
    base[(size_t)256 * KP + (size_t)n * KP + k] = lo;
}

// -------- Layer-0 mean aggregation -> split-bf16 planes directly --------
__global__ void agg0_kernel(const float* __restrict__ x, const int* __restrict__ off,
                            const int* __restrict__ csr,
                            u16* __restrict__ ahi, u16* __restrict__ alo) {
    int d = blockIdx.x;
    int tid = threadIdx.x;
    int c0 = tid, c1 = tid + 256, c2 = tid + 512;
    bool has2 = (c2 < IN_FEATS);
    float a0 = 0.f, a1 = 0.f, a2 = 0.f;
    int beg = off[d], end = off[d + 1];
    int e = beg;
    for (; e + 3 < end; e += 4) {      // 4-edge unroll: 12 loads in flight per thread
        const float* r0 = x + (size_t)csr[e]     * IN_FEATS;
        const float* r1 = x + (size_t)csr[e + 1] * IN_FEATS;
        const float* r2 = x + (size_t)csr[e + 2] * IN_FEATS;
        const float* r3 = x + (size_t)csr[e + 3] * IN_FEATS;
        float t00 = r0[c0], t10 = r1[c0], t20 = r2[c0], t30 = r3[c0];
        float t01 = r0[c1], t11 = r1[c1], t21 = r2[c1], t31 = r3[c1];
        float t02 = has2 ? r0[c2] : 0.f, t12 = has2 ? r1[c2] : 0.f;
        float t22 = has2 ? r2[c2] : 0.f, t32 = has2 ? r3[c2] : 0.f;
        a0 += (t00 + t10) + (t20 + t30);
        a1 += (t01 + t11) + (t21 + t31);
        a2 += (t02 + t12) + (t22 + t32);
    }
    for (; e < end; e++) {
        const float* r0 = x + (size_t)csr[e] * IN_FEATS;
        a0 += r0[c0];
        a1 += r0[c1];
        if (has2) a2 += r0[c2];
    }
    float inv = 1.f / fmaxf((float)(end - beg), 1.f);
    size_t base = (size_t)d * KP;
    u16 hi, lo;
    split_bf16(a0 * inv, hi, lo); ahi[base + c0] = hi; alo[base + c0] = lo;
    split_bf16(a1 * inv, hi, lo); ahi[base + c1] = hi; alo[base + c1] = lo;
    if (c2 < KP) {                     // tid<90: real features; tid 90..95: zero k-pad
        float v = has2 ? a2 * inv : 0.f;
        split_bf16(v, hi, lo); ahi[base + c2] = hi; alo[base + c2] = lo;
    }
}

// -------- Layer 0: h = relu(x@Wself0 + agg@Wneigh0 + b0) via split-bf16 MFMA --------
__global__ __launch_bounds__(256) void layer0_mfma(
        const u16* __restrict__ xhi, const u16* __restrict__ xlo,
        const u16* __restrict__ ghi, const u16* __restrict__ glo,
        const u16* __restrict__ wt, const float* __restrict__ b,
        float* __restrict__ h) {
    __shared__ u16 Ahi[64][LDT], Alo[64][LDT], Bhi[64][LDT], Blo[64][LDT];
    const int t    = threadIdx.x;
    const int lane = t & 63;
    const int w    = t >> 6;
    const int wm   = w >> 1, wn = w & 1;      // wave -> 32x32 quadrant
    const int row0 = blockIdx.x * 64;
    const int col0 = blockIdx.y * 64;
    const int sr   = t >> 2;                  // staging row/col 0..63
    const int sc   = (t & 3) * 8;             // staging k offset (8 ushorts = 16B)
    const int fr   = lane & 15;               // fragment row/col
    const int ko   = (lane >> 4) * 8;         // fragment k offset

    f32x4 acc[2][2] = {};

    for (int part = 0; part < 2; part++) {
        const u16* Aphi = part ? ghi : xhi;
        const u16* Aplo = part ? glo : xlo;
        const u16* Bphi = wt + (size_t)part * 2 * 256 * KP;
        const u16* Bplo = Bphi + (size_t)256 * KP;
        for (int k0 = 0; k0 < KP; k0 += 32) {
            short8 va = *reinterpret_cast<const short8*>(&Aphi[(size_t)(row0 + sr) * KP + k0 + sc]);
            short8 vb = *reinterpret_cast<const short8*>(&Aplo[(size_t)(row0 + sr) * KP + k0 + sc]);
            short8 vc = *reinterpret_cast<const short8*>(&Bphi[(size_t)(col0 + sr) * KP + k0 + sc]);
            short8 vd = *reinterpret_cast<const short8*>(&Bplo[(size_t)(col0 + sr) * KP + k0 + sc]);
            __syncthreads();   // previous step's LDS reads complete before overwrite
            *reinterpret_cast<short8*>(&Ahi[sr][sc]) = va;
            *reinterpret_cast<short8*>(&Alo[sr][sc]) = vb;
            *reinterpret_cast<short8*>(&Bhi[sr][sc]) = vc;
            *reinterpret_cast<short8*>(&Blo[sr][sc]) = vd;
            __syncthreads();
            short8 bh[2], bl[2];
#pragma unroll
            for (int n = 0; n < 2; n++) {
                bh[n] = *reinterpret_cast<const short8*>(&Bhi[wn * 32 + n * 16 + fr][ko]);
                bl[n] = *reinterpret_cast<const short8*>(&Blo[wn * 32 + n * 16 + fr][ko]);
            }
#pragma unroll
            for (int m = 0; m < 2; m++) {
                short8 ah = *reinterpret_cast<const short8*>(&Ahi[wm * 32 + m * 16 + fr][ko]);
                short8 al = *reinterpret_cast<const short8*>(&Alo[wm * 32 + m * 16 + fr][ko]);
#pragma unroll
                for (int n = 0; n < 2; n++) {
                    acc[m][n] = __builtin_amdgcn_mfma_f32_16x16x32_bf16(ah, bh[n], acc[m][n], 0, 0, 0);
                    acc[m][n] = __builtin_amdgcn_mfma_f32_16x16x32_bf16(ah, bl[n], acc[m][n], 0, 0, 0);
                    acc[m][n] = __builtin_amdgcn_mfma_f32_16x16x32_bf16(al, bh[n], acc[m][n], 0, 0, 0);
                }
            }
        }
    }
    const int fq = lane >> 4;
#pragma unroll
    for (int m = 0; m < 2; m++) {
#pragma unroll
        for (int n = 0; n < 2; n++) {
            int gcol = col0 + wn * 32 + n * 16 + fr;
            float bc = b[gcol];
#pragma unroll
            for (int r = 0; r < 4; r++) {
                int grow = row0 + wm * 32 + m * 16 + fq * 4 + r;
                if (grow < N_DST0)
                    h[(size_t)grow * N_HIDDEN + gcol] = fmaxf(acc[m][n][r] + bc, 0.f);
            }
        }
    }
}

// -------- Layer-1 mean aggregation over h (256-dim): one block per dst --------
__global__ void agg1_kernel(const float* __restrict__ h, const int* __restrict__ off,
                            const int* __restrict__ csr, float* __restrict__ agg) {
    int d = blockIdx.x;
    int tid = threadIdx.x;
    float a = 0.f;
    int beg = off[d], end = off[d + 1];
    for (int e = beg; e < end; e++)
        a += h[(size_t)csr[e] * N_HIDDEN + tid];
    agg[(size_t)d * N_HIDDEN + tid] = a / fmaxf((float)(end - beg), 1.f);
}

// -------- Layer 1: out = h[:N_DST1] @ Wself1 + agg1 @ Wneigh1 + b1 --------
__global__ void layer1_kernel(const float* __restrict__ h, const float* __restrict__ agg1,
                              const float* __restrict__ Wself, const float* __restrict__ Wneigh,
                              const float* __restrict__ b, float* __restrict__ out) {
    int idx = blockIdx.x * blockDim.x + threadIdx.x;
    if (idx >= N_DST1 * N_CLASSES) return;
    int d = idx / N_CLASSES, c = idx % N_CLASSES;
    const float* hd = h + (size_t)d * N_HIDDEN;
    const float* ha = agg1 + (size_t)d * N_HIDDEN;
    float acc = b[c];
    for (int k = 0; k < N_HIDDEN; k++)
        acc += hd[k] * Wself[k * N_CLASSES + c] + ha[k] * Wneigh[k * N_CLASSES + c];
    out[idx] = acc;
}

extern "C" void kernel_launch(void* const* d_in, const int* in_sizes, int n_in,
                              void* d_out, int out_size, void* d_ws, size_t ws_size,
                              hipStream_t stream) {
    const float* x       = (const float*)d_in[0];
    const float* Wself0  = (const float*)d_in[1];
    const float* Wneigh0 = (const float*)d_in[2];
    const float* b0      = (const float*)d_in[3];
    const float* Wself1  = (const float*)d_in[4];
    const float* Wneigh1 = (const float*)d_in[5];
    const float* b1      = (const float*)d_in[6];
    const int* e0_src = (const int*)d_in[7];
    const int* e0_dst = (const int*)d_in[8];
    const int* e1_src = (const int*)d_in[9];
    const int* e1_dst = (const int*)d_in[10];

    char* ws = (char*)d_ws;
    size_t o = 0;
    auto alloc = [&](size_t bytes) -> void* {
        void* p = ws + o;
        o = (o + bytes + 255) & ~(size_t)255;
        return p;
    };
    int* cnt_block = (int*)alloc((size_t)(N_DST0 + N_DST0 + N_DST1 + N_DST1) * sizeof(int));
    int* cnt0 = cnt_block;
    int* cur0 = cnt_block + N_DST0;
    int* cnt1 = cnt_block + 2 * N_DST0;
    int* cur1 = cnt_block + 2 * N_DST0 + N_DST1;
    int* off0 = (int*)alloc((size_t)(N_DST0 + 1) * sizeof(int));
    int* off1 = (int*)alloc((size_t)(N_DST1 + 1) * sizeof(int));
    int* csr0 = (int*)alloc((size_t)N_E0 * sizeof(int));
    int* csr1 = (int*)alloc((size_t)N_E1 * sizeof(int));
    u16* xhi = (u16*)alloc((size_t)MP * KP * sizeof(u16));
    u16* xlo = (u16*)alloc((size_t)MP * KP * sizeof(u16));
    u16* ahi = (u16*)alloc((size_t)MP * KP * sizeof(u16));
    u16* alo = (u16*)alloc((size_t)MP * KP * sizeof(u16));
    u16* wt  = (u16*)alloc((size_t)2 * 2 * 256 * KP * sizeof(u16));
    float* h    = (float*)alloc((size_t)N_DST0 * N_HIDDEN * sizeof(float));
    float* agg1 = (float*)alloc((size_t)N_DST1 * N_HIDDEN * sizeof(float));

    hipMemsetAsync(cnt_block, 0, (size_t)(2 * N_DST0 + 2 * N_DST1) * sizeof(int), stream);

    int total_e = N_E0 + N_E1;
    count_kernel<<<(total_e + 255) / 256, 256, 0, stream>>>(e0_dst, N_E0, cnt0, e1_dst, N_E1, cnt1);
    scan_kernel<<<2, 1024, 0, stream>>>(cnt0, off0, N_DST0, cnt1, off1, N_DST1);
    fill_kernel<<<(total_e + 255) / 256, 256, 0, stream>>>(e0_src, e0_dst, N_E0, off0, cur0, csr0,
                                                           e1_src, e1_dst, N_E1, off1, cur1, csr1);
    xconv_kernel<<<(N_DST0 * KP + 255) / 256, 256, 0, stream>>>(x, xhi, xlo);
    wconv_kernel<<<(2 * KP * 256 + 255) / 256, 256, 0, stream>>>(Wself0, Wneigh0, wt);
    agg0_kernel<<<N_DST0, 256, 0, stream>>>(x, off0, csr0, ahi, alo);
    dim3 g0(MP / 64, N_HIDDEN / 64);
    layer0_mfma<<<g0, 256, 0, stream>>>(xhi, xlo, ahi, alo, wt, b0, h);
    agg1_kernel<<<N_DST1, 256, 0, stream>>>(h, off1, csr1, agg1);
    layer1_kernel<<<(N_DST1 * N_CLASSES + 255) / 256, 256, 0, stream>>>(h, agg1, Wself1, Wneigh1, b1,
                                                                        (float*)d_out);
}

// Round 2
// 978.052 us; speedup vs baseline: 1.2247x; 1.0230x over previous
//
#include <hip/hip_runtime.h>

#define N_SRC0   286000
#define N_DST0   11000
#define N_E0     275000
#define N_DST1   1000
#define N_E1     10000
#define IN_FEATS 602
#define N_HIDDEN 256
#define N_CLASSES 41

#define KP 608            // IN_FEATS padded to multiple of 32 (mfma K)
#define MP 11008          // N_DST0 padded to multiple of 64 (tile M)
#define LDT 40            // LDS row length in ushorts: 32 + 8 pad -> 80B rows, balanced b128 spans

typedef unsigned short u16;
typedef __attribute__((ext_vector_type(8))) short short8;
typedef __attribute__((ext_vector_type(4))) float f32x4;

__device__ inline void split_bf16(float v, u16& hi, u16& lo) {
    unsigned u = __float_as_uint(v);
    unsigned r = u + 0x7FFFu + ((u >> 16) & 1u);      // RNE to bf16
    hi = (u16)(r >> 16);
    float vhi = __uint_as_float((unsigned)hi << 16);
    float vl = v - vhi;
    unsigned u2 = __float_as_uint(vl);
    unsigned r2 = u2 + 0x7FFFu + ((u2 >> 16) & 1u);
    lo = (u16)(r2 >> 16);
}

// -------- fused prep: edge-count histogram + weight conversion --------
// count part: atomics into cnt0/cnt1.  wconv part: W[k][n] fp32 ->
// wt[part][plane][n][KP] bf16 (n-major so layer0 stages contiguous k-runs).
#define NB_COUNT ((N_E0 + N_E1 + 255) / 256)
#define NB_WCONV ((2 * KP * 256) / 256)

__global__ void prep_kernel(const int* __restrict__ d0, int* __restrict__ c0,
                            const int* __restrict__ d1, int* __restrict__ c1,
                            const float* __restrict__ Wself, const float* __restrict__ Wneigh,
                            u16* __restrict__ wt) {
    int bid = blockIdx.x;
    if (bid < NB_COUNT) {
        int i = bid * 256 + threadIdx.x;
        if (i < N_E0) {
            atomicAdd(&c0[d0[i]], 1);
        } else {
            int j = i - N_E0;
            if (j < N_E1) atomicAdd(&c1[d1[j]], 1);
        }
    } else {
        int idx = (bid - NB_COUNT) * 256 + threadIdx.x;   // over 2*KP*256, n fastest
        int part = idx / (KP * 256);
        int rem  = idx - part * (KP * 256);
        int k = rem / 256;
        int n = rem - k * 256;
        float v = (k < IN_FEATS) ? (part ? Wneigh[(size_t)k * 256 + n] : Wself[(size_t)k * 256 + n]) : 0.f;
        u16 hi, lo; split_bf16(v, hi, lo);
        u16* base = wt + (size_t)part * 2 * 256 * KP;
        base[(size_t)n * KP + k] = hi;
        base[(size_t)256 * KP + (size_t)n * KP + k] = lo;
    }
}

__global__ void scan_kernel(const int* __restrict__ cnt0, int* __restrict__ off0, int n0_,
                            const int* __restrict__ cnt1, int* __restrict__ off1, int n1_) {
    const int* cnt; int* off; int n;
    if (blockIdx.x == 0) { cnt = cnt0; off = off0; n = n0_; }
    else                 { cnt = cnt1; off = off1; n = n1_; }
    __shared__ int sums[1024];
    int tid = threadIdx.x;
    int chunk = (n + 1023) >> 10;
    int start = tid * chunk;
    int end = min(start + chunk, n);
    int s = 0;
    for (int i = start; i < end; i++) s += cnt[i];
    sums[tid] = s;
    __syncthreads();
    for (int d = 1; d < 1024; d <<= 1) {
        int v = (tid >= d) ? sums[tid - d] : 0;
        __syncthreads();
        sums[tid] += v;
        __syncthreads();
    }
    int run = (tid > 0) ? sums[tid - 1] : 0;
    for (int i = start; i < end; i++) { off[i] = run; run += cnt[i]; }
    if (tid == 1023) off[n] = run;
}

__global__ void fill_kernel(const int* __restrict__ s0, const int* __restrict__ d0, int n0,
                            const int* __restrict__ off0, int* __restrict__ cur0, int* __restrict__ csr0,
                            const int* __restrict__ s1, const int* __restrict__ d1, int n1,
                            const int* __restrict__ off1, int* __restrict__ cur1, int* __restrict__ csr1) {
    int i = blockIdx.x * blockDim.x + threadIdx.x;
    if (i < n0) {
        int d = d0[i];
        int p = atomicAdd(&cur0[d], 1);
        csr0[off0[d] + p] = s0[i];
    } else {
        int j = i - n0;
        if (j < n1) {
            int d = d1[j];
            int p = atomicAdd(&cur1[d], 1);
            csr1[off1[d] + p] = s1[j];
        }
    }
}

// -------- Layer-0 mean aggregation -> split-bf16 planes, float2 gather --------
// Row = 301 float2 (8B-aligned). Thread t covers float2 idx t, and 256+t for t<45.
__global__ void agg0_kernel(const float* __restrict__ x, const int* __restrict__ off,
                            const int* __restrict__ csr,
                            u16* __restrict__ ahi, u16* __restrict__ alo) {
    int d = blockIdx.x;
    int t = threadIdx.x;
    const bool has1 = (t < 45);                 // float2 idx 256..300 (cols 512..601)
    const float2* X = (const float2*)x;         // row r starts at float2 r*301
    float a0x = 0.f, a0y = 0.f, a1x = 0.f, a1y = 0.f;
    int beg = off[d], end = off[d + 1];
    int e = beg;
    for (; e + 3 < end; e += 4) {
        const float2* p0 = X + (size_t)csr[e]     * 301;
        const float2* p1 = X + (size_t)csr[e + 1] * 301;
        const float2* p2 = X + (size_t)csr[e + 2] * 301;
        const float2* p3 = X + (size_t)csr[e + 3] * 301;
        float2 u0 = p0[t], u1 = p1[t], u2 = p2[t], u3 = p3[t];
        if (has1) {
            float2 w0 = p0[256 + t], w1 = p1[256 + t], w2 = p2[256 + t], w3 = p3[256 + t];
            a1x += (w0.x + w1.x) + (w2.x + w3.x);
            a1y += (w0.y + w1.y) + (w2.y + w3.y);
        }
        a0x += (u0.x + u1.x) + (u2.x + u3.x);
        a0y += (u0.y + u1.y) + (u2.y + u3.y);
    }
    for (; e < end; e++) {
        const float2* p0 = X + (size_t)csr[e] * 301;
        float2 u0 = p0[t];
        a0x += u0.x; a0y += u0.y;
        if (has1) { float2 w0 = p0[256 + t]; a1x += w0.x; a1y += w0.y; }
    }
    float inv = 1.f / fmaxf((float)(end - beg), 1.f);
    size_t base = (size_t)d * KP;
    u16 h0, l0, h1, l1;
    split_bf16(a0x * inv, h0, l0);
    split_bf16(a0y * inv, h1, l1);
    *(unsigned*)&ahi[base + 2 * t] = (unsigned)h0 | ((unsigned)h1 << 16);
    *(unsigned*)&alo[base + 2 * t] = (unsigned)l0 | ((unsigned)l1 << 16);
    if (has1) {
        split_bf16(a1x * inv, h0, l0);
        split_bf16(a1y * inv, h1, l1);
        *(unsigned*)&ahi[base + 512 + 2 * t] = (unsigned)h0 | ((unsigned)h1 << 16);
        *(unsigned*)&alo[base + 512 + 2 * t] = (unsigned)l0 | ((unsigned)l1 << 16);
    } else if (t < 48) {                        // zero k-pad, cols 602..607
        *(unsigned*)&ahi[base + 512 + 2 * t] = 0u;
        *(unsigned*)&alo[base + 512 + 2 * t] = 0u;
    }
}

// -------- Layer 0: h = relu(x@Wself0 + agg@Wneigh0 + b0), split-bf16 MFMA --------
// Part 0 stages fp32 x directly (register split -> both planes; no xconv pass).
// 1-deep register prefetch: store(k) -> barrier -> issue loads(k+1) -> MFMA(k),
// so global latency hides under the compute phase instead of stalling at the
// pre-write vmcnt(0).
__global__ __launch_bounds__(256) void layer0_mfma(
        const float* __restrict__ x,
        const u16* __restrict__ ghi, const u16* __restrict__ glo,
        const u16* __restrict__ wt, const float* __restrict__ b,
        float* __restrict__ h) {
    __shared__ u16 Ahi[64][LDT], Alo[64][LDT], Bhi[64][LDT], Blo[64][LDT];
    const int t    = threadIdx.x;
    const int lane = t & 63;
    const int w    = t >> 6;
    const int wm   = w >> 1, wn = w & 1;      // wave -> 32x32 quadrant
    const int row0 = blockIdx.x * 64;
    const int col0 = blockIdx.y * 64;
    const int sr   = t >> 2;                  // staging row/col 0..63
    const int sc   = (t & 3) * 8;             // staging k offset (8 elems = 16B bf16 / 32B fp32)
    const int fr   = lane & 15;               // fragment row/col
    const int ko   = (lane >> 4) * 8;         // fragment k offset

    const u16* wt0 = wt;
    const u16* wt1 = wt + (size_t)2 * 256 * KP;

    f32x4 acc[2][2] = {};

    // prefetch registers
    float2 fa[4];              // part-0 A: 8 fp32
    short8 pah, pal;           // part-1 A planes
    short8 pbh, pbl;           // B planes

    auto load0 = [&](int k0) {
        const float* ap = x + (size_t)(row0 + sr) * IN_FEATS + k0 + sc;
        fa[0] = *(const float2*)(ap + 0);
        fa[1] = *(const float2*)(ap + 2);
        fa[2] = *(const float2*)(ap + 4);
        fa[3] = *(const float2*)(ap + 6);
        const u16* bp = wt0 + (size_t)(col0 + sr) * KP + k0 + sc;
        pbh = *(const short8*)bp;
        pbl = *(const short8*)(bp + (size_t)256 * KP);
    };
    auto load1 = [&](int k0) {
        size_t ao = (size_t)(row0 + sr) * KP + k0 + sc;
        pah = *(const short8*)(ghi + ao);
        pal = *(const short8*)(glo + ao);
        const u16* bp = wt1 + (size_t)(col0 + sr) * KP + k0 + sc;
        pbh = *(const short8*)bp;
        pbl = *(const short8*)(bp + (size_t)256 * KP);
    };
    auto store0 = [&]() {
        short8 hv, lv;
#pragma unroll
        for (int j = 0; j < 4; j++) {
            u16 h0, l0, h1, l1;
            split_bf16(fa[j].x, h0, l0);
            split_bf16(fa[j].y, h1, l1);
            hv[2 * j] = (short)h0; hv[2 * j + 1] = (short)h1;
            lv[2 * j] = (short)l0; lv[2 * j + 1] = (short)l1;
        }
        *(short8*)&Ahi[sr][sc] = hv;
        *(short8*)&Alo[sr][sc] = lv;
        *(short8*)&Bhi[sr][sc] = pbh;
        *(short8*)&Blo[sr][sc] = pbl;
    };
    auto store1 = [&]() {
        *(short8*)&Ahi[sr][sc] = pah;
        *(short8*)&Alo[sr][sc] = pal;
        *(short8*)&Bhi[sr][sc] = pbh;
        *(short8*)&Blo[sr][sc] = pbl;
    };
    auto compute = [&]() {
        short8 bh[2], bl[2];
#pragma unroll
        for (int n = 0; n < 2; n++) {
            bh[n] = *(const short8*)&Bhi[wn * 32 + n * 16 + fr][ko];
            bl[n] = *(const short8*)&Blo[wn * 32 + n * 16 + fr][ko];
        }
#pragma unroll
        for (int m = 0; m < 2; m++) {
            short8 ah = *(const short8*)&Ahi[wm * 32 + m * 16 + fr][ko];
            short8 al = *(const short8*)&Alo[wm * 32 + m * 16 + fr][ko];
#pragma unroll
            for (int n = 0; n < 2; n++) {
                acc[m][n] = __builtin_amdgcn_mfma_f32_16x16x32_bf16(ah, bh[n], acc[m][n], 0, 0, 0);
                acc[m][n] = __builtin_amdgcn_mfma_f32_16x16x32_bf16(ah, bl[n], acc[m][n], 0, 0, 0);
                acc[m][n] = __builtin_amdgcn_mfma_f32_16x16x32_bf16(al, bh[n], acc[m][n], 0, 0, 0);
            }
        }
    };

    load0(0);
    for (int s = 0; s < KP / 32; s++) {        // part 0: x @ Wself
        __syncthreads();                       // prior step's LDS reads done
        store0();
        __syncthreads();
        if (s < KP / 32 - 1) load0((s + 1) * 32);
        else                 load1(0);         // bridge into part 1
        compute();
    }
    for (int s = 0; s < KP / 32; s++) {        // part 1: agg @ Wneigh
        __syncthreads();
        store1();
        __syncthreads();
        if (s < KP / 32 - 1) load1((s + 1) * 32);
        compute();
    }

    const int fq = lane >> 4;
#pragma unroll
    for (int m = 0; m < 2; m++) {
#pragma unroll
        for (int n = 0; n < 2; n++) {
            int gcol = col0 + wn * 32 + n * 16 + fr;
            float bc = b[gcol];
#pragma unroll
            for (int r = 0; r < 4; r++) {
                int grow = row0 + wm * 32 + m * 16 + fq * 4 + r;
                if (grow < N_DST0)
                    h[(size_t)grow * N_HIDDEN + gcol] = fmaxf(acc[m][n][r] + bc, 0.f);
            }
        }
    }
}

// -------- fused layer 1: mean-agg over h + GEMV to 41 classes --------
__global__ __launch_bounds__(256) void fused_l1(
        const float* __restrict__ h, const int* __restrict__ off, const int* __restrict__ csr,
        const float* __restrict__ Wself, const float* __restrict__ Wneigh,
        const float* __restrict__ b, float* __restrict__ out) {
    __shared__ float sh[N_HIDDEN], sa[N_HIDDEN];
    int d = blockIdx.x;
    int t = threadIdx.x;
    float a = 0.f;
    int beg = off[d], end = off[d + 1];
    for (int e = beg; e < end; e++)
        a += h[(size_t)csr[e] * N_HIDDEN + t];
    sa[t] = a / fmaxf((float)(end - beg), 1.f);
    sh[t] = h[(size_t)d * N_HIDDEN + t];
    __syncthreads();
    if (t < N_CLASSES) {
        float acc = b[t];
        for (int k = 0; k < N_HIDDEN; k++)
            acc += sh[k] * Wself[k * N_CLASSES + t] + sa[k] * Wneigh[k * N_CLASSES + t];
        out[(size_t)d * N_CLASSES + t] = acc;
    }
}

extern "C" void kernel_launch(void* const* d_in, const int* in_sizes, int n_in,
                              void* d_out, int out_size, void* d_ws, size_t ws_size,
                              hipStream_t stream) {
    const float* x       = (const float*)d_in[0];
    const float* Wself0  = (const float*)d_in[1];
    const float* Wneigh0 = (const float*)d_in[2];
    const float* b0      = (const float*)d_in[3];
    const float* Wself1  = (const float*)d_in[4];
    const float* Wneigh1 = (const float*)d_in[5];
    const float* b1      = (const float*)d_in[6];
    const int* e0_src = (const int*)d_in[7];
    const int* e0_dst = (const int*)d_in[8];
    const int* e1_src = (const int*)d_in[9];
    const int* e1_dst = (const int*)d_in[10];

    char* ws = (char*)d_ws;
    size_t o = 0;
    auto alloc = [&](size_t bytes) -> void* {
        void* p = ws + o;
        o = (o + bytes + 255) & ~(size_t)255;
        return p;
    };
    int* cnt_block = (int*)alloc((size_t)(N_DST0 + N_DST0 + N_DST1 + N_DST1) * sizeof(int));
    int* cnt0 = cnt_block;
    int* cur0 = cnt_block + N_DST0;
    int* cnt1 = cnt_block + 2 * N_DST0;
    int* cur1 = cnt_block + 2 * N_DST0 + N_DST1;
    int* off0 = (int*)alloc((size_t)(N_DST0 + 1) * sizeof(int));
    int* off1 = (int*)alloc((size_t)(N_DST1 + 1) * sizeof(int));
    int* csr0 = (int*)alloc((size_t)N_E0 * sizeof(int));
    int* csr1 = (int*)alloc((size_t)N_E1 * sizeof(int));
    u16* ahi = (u16*)alloc((size_t)MP * KP * sizeof(u16));
    u16* alo = (u16*)alloc((size_t)MP * KP * sizeof(u16));
    u16* wt  = (u16*)alloc((size_t)2 * 2 * 256 * KP * sizeof(u16));
    float* h = (float*)alloc((size_t)N_DST0 * N_HIDDEN * sizeof(float));

    hipMemsetAsync(cnt_block, 0, (size_t)(2 * N_DST0 + 2 * N_DST1) * sizeof(int), stream);

    int total_e = N_E0 + N_E1;
    prep_kernel<<<NB_COUNT + NB_WCONV, 256, 0, stream>>>(e0_dst, cnt0, e1_dst, cnt1,
                                                         Wself0, Wneigh0, wt);
    scan_kernel<<<2, 1024, 0, stream>>>(cnt0, off0, N_DST0, cnt1, off1, N_DST1);
    fill_kernel<<<(total_e + 255) / 256, 256, 0, stream>>>(e0_src, e0_dst, N_E0, off0, cur0, csr0,
                                                           e1_src, e1_dst, N_E1, off1, cur1, csr1);
    agg0_kernel<<<N_DST0, 256, 0, stream>>>(x, off0, csr0, ahi, alo);
    dim3 g0(MP / 64, N_HIDDEN / 64);
    layer0_mfma<<<g0, 256, 0, stream>>>(x, ahi, alo, wt, b0, h);
    fused_l1<<<N_DST1, 256, 0, stream>>>(h, off1, csr1, Wself1, Wneigh1, b1, (float*)d_out);
}